// Round 14
// baseline (343.006 us; speedup 1.0000x reference)
//
#include <hip/hip_runtime.h>
#include <hip/hip_bf16.h>

#define N_NODES 100000
#define N_EDGES 1600000
#define F_IN 64
#define HID 128
#define HEAD_H 256
#define OUT_F 32
#define N_GRAPHS 512
#define NBK 98        // coarse buckets (dst >> 10)
#define SLOT 20480    // fixed records per bucket (mean 16384, sigma ~127)
#define BCHUNK 2048   // edges per bin-kernel block
#define NCHUNKS ((N_EDGES + BCHUNK - 1) / BCHUNK)  // 782
#define CAST_BLOCKS (N_NODES * F_IN / 2 / 256)     // 12500

typedef float f2v __attribute__((ext_vector_type(2)));
typedef short bf16x8 __attribute__((ext_vector_type(8)));
typedef float f32x4 __attribute__((ext_vector_type(4)));

__device__ __forceinline__ float leaky(float v) {
    return v >= 0.f ? v : 0.01f * v;
}

__device__ __forceinline__ float bf2f(ushort u) {
    union { uint i; float f; } c; c.i = ((uint)u) << 16; return c.f;
}

__device__ __forceinline__ ushort f2bf(float f) {
    union { float f; uint i; } c; c.f = f;
    uint r = c.i + 0x7FFF + ((c.i >> 16) & 1);
    return (ushort)(r >> 16);
}

// ---------------- setup: cast x -> bf16 AND prep transposed bf16 weights (one dispatch) ----------------
__global__ __launch_bounds__(256) void setup_kernel(const float* __restrict__ x,
                                                    ushort* __restrict__ xb,
                                                    const float* __restrict__ Wn0,
                                                    const float* __restrict__ Wn1,
                                                    const float* __restrict__ Wn2,
                                                    ushort* __restrict__ w0T,
                                                    ushort* __restrict__ w1T,
                                                    ushort* __restrict__ w2T) {
    int b = blockIdx.x;
    if (b < CAST_BLOCKS) {
        int i = b * 256 + threadIdx.x;  // handles 2 elems
        float2 v = ((const float2*)x)[i];
        uint u = (uint)f2bf(v.x) | ((uint)f2bf(v.y) << 16);
        ((uint*)xb)[i] = u;
    } else {
        int id = (b - CAST_BLOCKS) * 256 + threadIdx.x;
        if (id < 128 * 64) {
            int j = id / 64, k = id % 64;
            w0T[id] = f2bf(Wn0[k * 128 + j]);
        } else if (id < 128 * 64 + 128 * 128) {
            int t = id - 128 * 64; int j = t / 128, k = t % 128;
            w1T[t] = f2bf(Wn1[k * 128 + j]);
        } else if (id < 128 * 64 + 2 * 128 * 128) {
            int t = id - 128 * 64 - 128 * 128; int j = t / 128, k = t % 128;
            w2T[t] = f2bf(Wn2[k * 128 + j]);
        }
    }
}

// ---------------- slotted-bucket CSR build ----------------
// bcur[b] holds COUNTS (memset 0); slot base b*SLOT added where needed.

// pass 1: bin edges by dst>>10 into fixed bucket slots of recs1
// record: x = src | (dloc<<22), y = packed bf16 edge attrs. Order within bucket arbitrary.
__global__ __launch_bounds__(256) void bin_kernel(const int* __restrict__ src,
                                                  const int* __restrict__ dst,
                                                  const float2* __restrict__ ea,
                                                  int* __restrict__ bcur,
                                                  uint2* __restrict__ recs1) {
    __shared__ int hist[NBK], tmp[NBK], offs[NBK], cur[NBK], gbase[NBK];
    __shared__ uint2 stage[BCHUNK];
    __shared__ unsigned char sbid[BCHUNK];

    int tid = threadIdx.x;
    int e0 = blockIdx.x * BCHUNK;
    int nn = N_EDGES - e0; if (nn > BCHUNK) nn = BCHUNK;  // 2048 or 512, both %4==0

    if (tid < NBK) hist[tid] = 0;
    __syncthreads();

    // phase A: LDS histogram over this chunk (int4 loads)
    for (int i0 = tid * 4; i0 < nn; i0 += 1024) {
        int4 d4 = *(const int4*)(dst + e0 + i0);
        atomicAdd(&hist[d4.x >> 10], 1);
        atomicAdd(&hist[d4.y >> 10], 1);
        atomicAdd(&hist[d4.z >> 10], 1);
        atomicAdd(&hist[d4.w >> 10], 1);
    }
    __syncthreads();

    // scan hist -> offs (exclusive)
    if (tid < NBK) tmp[tid] = hist[tid];
    __syncthreads();
    for (int off = 1; off < NBK; off <<= 1) {
        int u = (tid < NBK && tid >= off) ? tmp[tid - off] : 0;
        __syncthreads();
        if (tid < NBK) tmp[tid] += u;
        __syncthreads();
    }
    if (tid < NBK) {
        int ex = tmp[tid] - hist[tid];
        offs[tid] = ex;
        cur[tid] = ex;
        gbase[tid] = (hist[tid] > 0) ? (tid * SLOT + atomicAdd(&bcur[tid], hist[tid])) : 0;
    }
    __syncthreads();

    // phase B: place records into LDS, bucket-sorted (vectorized loads)
    for (int i0 = tid * 4; i0 < nn; i0 += 1024) {
        int e = e0 + i0;
        int4 d4 = *(const int4*)(dst + e);
        int4 s4 = *(const int4*)(src + e);
        float4 ea01 = *(const float4*)(ea + e);
        float4 ea23 = *(const float4*)(ea + e + 2);
#pragma unroll
        for (int k = 0; k < 4; k++) {
            int d = (k == 0) ? d4.x : (k == 1) ? d4.y : (k == 2) ? d4.z : d4.w;
            int s = (k == 0) ? s4.x : (k == 1) ? s4.y : (k == 2) ? s4.z : s4.w;
            float aex = (k == 0) ? ea01.x : (k == 1) ? ea01.z : (k == 2) ? ea23.x : ea23.z;
            float aey = (k == 0) ? ea01.y : (k == 1) ? ea01.w : (k == 2) ? ea23.y : ea23.w;
            int b = d >> 10;
            uint2 r;
            r.x = (uint)s | ((uint)(d & 1023) << 22);
            r.y = (uint)f2bf(aex) | ((uint)f2bf(aey) << 16);
            int pos = atomicAdd(&cur[b], 1);
            stage[pos] = r;
            sbid[pos] = (unsigned char)b;
        }
    }
    __syncthreads();

    // phase C: flush contiguous per-bucket runs
    for (int i = tid; i < nn; i += 256) {
        int b = sbid[i];
        recs1[gbase[b] + (i - offs[b])] = stage[i];
    }
}

// pass 2: per bucket, build rr[{beg,end}] (LDS) + order records into exact slots of recs2
__global__ __launch_bounds__(256) void order_kernel(const uint2* __restrict__ recs1,
                                                    const int* __restrict__ bcur,
                                                    int* __restrict__ rr,
                                                    uint2* __restrict__ recs2) {
    __shared__ int h[1024];
    __shared__ int ssum[256];
    int b = blockIdx.x;
    int tid = threadIdx.x;
    int base = b * SLOT;
    int end = base + bcur[b];

    for (int i = tid; i < 1024; i += 256) h[i] = 0;
    __syncthreads();

    // LDS histogram of node-local ids over this bucket's filled region
    for (int t = base + tid; t < end; t += 256) {
        atomicAdd(&h[recs1[t].x >> 22], 1);
    }
    __syncthreads();

    // scan 1024 in LDS: thread owns 4 entries + 256-ladder
    int i4 = tid * 4;
    int a0 = h[i4], a1 = h[i4 + 1], a2 = h[i4 + 2], a3 = h[i4 + 3];
    int s = a0 + a1 + a2 + a3;
    ssum[tid] = s;
    __syncthreads();
    for (int off = 1; off < 256; off <<= 1) {
        int u = (tid >= off) ? ssum[tid - off] : 0;
        __syncthreads();
        ssum[tid] += u;
        __syncthreads();
    }
    int pre = base + ssum[tid] - s;  // absolute exclusive prefix within slotted space
    int c0 = pre, c1 = pre + a0, c2 = c1 + a1, c3 = c2 + a2;
    h[i4] = c0; h[i4 + 1] = c1; h[i4 + 2] = c2; h[i4 + 3] = c3;

    // write rr (beg,end interleaved) for this bucket's nodes
    int n = (b << 10) + i4;
    if (n + 4 <= N_NODES) {
        *(int4*)(rr + 2 * n)     = make_int4(c0, c0 + a0, c1, c1 + a1);
        *(int4*)(rr + 2 * n + 4) = make_int4(c2, c2 + a2, c3, c3 + a3);
    } else {
        if (n + 0 < N_NODES) { rr[2 * n + 0] = c0; rr[2 * n + 1] = c0 + a0; }
        if (n + 1 < N_NODES) { rr[2 * n + 2] = c1; rr[2 * n + 3] = c1 + a1; }
        if (n + 2 < N_NODES) { rr[2 * n + 4] = c2; rr[2 * n + 5] = c2 + a2; }
        if (n + 3 < N_NODES) { rr[2 * n + 6] = c3; rr[2 * n + 7] = c3 + a3; }
    }
    __syncthreads();

    // place records into exact slots
    for (int t = base + tid; t < end; t += 256) {
        uint2 r = recs1[t];
        int pos = atomicAdd(&h[r.x >> 22], 1);
        recs2[pos] = make_uint2(r.x & 0x3FFFFFu, r.y);
    }
}

// ---------------- fused GINE layer (pipelined node stealing + LDS tile + MFMA epilogue) ----------------
// 256 threads = 4 waves; block owns 16 nodes. Waves steal nodes from an LDS counter;
// the NEXT node's steal + {beg,end} load are issued BEFORE processing the current
// node's edges, hiding the ~1000-cycle setup chain under edge streaming.

template <int K>
__global__ __launch_bounds__(256) void gine_fused(const ushort* __restrict__ xb,
                                                  const uint2* __restrict__ recs,
                                                  const int* __restrict__ rr,
                                                  const float* __restrict__ We,
                                                  const float* __restrict__ be,
                                                  const ushort* __restrict__ wnT,
                                                  const float* __restrict__ bn,
                                                  ushort* __restrict__ hb) {
    __shared__ float tile[16 * K];
    __shared__ int node_ctr;
    int tid = threadIdx.x;
    int wave = tid >> 6;
    int lane = tid & 63;
    int n0 = blockIdx.x * 16;

    if (tid == 0) node_ctr = 0;
    __syncthreads();

    auto steal = [&]() -> int {
        int q = 0;
        if (lane == 0) q = atomicAdd(&node_ctr, 1);
        return __builtin_amdgcn_readfirstlane(q);
    };

    // ---- gather phase: pipelined dynamic node grab ----
    if constexpr (K == 128) {
        int j = lane * 2;
        f2v w0v = {We[j], We[j + 1]};
        f2v w1v = {We[128 + j], We[128 + j + 1]};
        f2v bbv = {be[j], be[j + 1]};
        const f2v zero = {0.f, 0.f};

        int q = steal();
        int rs = 0, re = 0;
        if (q < 16) {
            rs = __builtin_amdgcn_readfirstlane(rr[2 * (n0 + q)]);
            re = __builtin_amdgcn_readfirstlane(rr[2 * (n0 + q) + 1]);
        }
        while (q < 16) {
            int q2 = steal();
            int rs2 = 0, re2 = 0;
            if (q2 < 16) {
                rs2 = __builtin_amdgcn_readfirstlane(rr[2 * (n0 + q2)]);
                re2 = __builtin_amdgcn_readfirstlane(rr[2 * (n0 + q2) + 1]);
            }
            f2v accv = {0.f, 0.f};

            auto proc = [&](uint2 r, uint u) {
                float ax = bf2f((ushort)(r.y & 0xFFFF));
                float ay = bf2f((ushort)(r.y >> 16));
                union { uint i; float f; } lo, hi;
                lo.i = u << 16;
                hi.i = u & 0xFFFF0000u;
                f2v xv = {lo.f, hi.f};
                f2v m = xv + bbv;
                m = ay * w1v + m;
                m = ax * w0v + m;
                m = __builtin_elementwise_max(m, zero);
                accv += m;
            };

            int t = rs;
            for (; t + 7 < re; t += 8) {
                uint2 r0 = recs[t];
                uint2 r1 = recs[t + 1];
                uint2 r2 = recs[t + 2];
                uint2 r3 = recs[t + 3];
                uint2 r4 = recs[t + 4];
                uint2 r5 = recs[t + 5];
                uint2 r6 = recs[t + 6];
                uint2 r7 = recs[t + 7];
                uint u0 = *(const uint*)(xb + (size_t)r0.x * 128 + j);
                uint u1 = *(const uint*)(xb + (size_t)r1.x * 128 + j);
                uint u2 = *(const uint*)(xb + (size_t)r2.x * 128 + j);
                uint u3 = *(const uint*)(xb + (size_t)r3.x * 128 + j);
                uint u4 = *(const uint*)(xb + (size_t)r4.x * 128 + j);
                uint u5 = *(const uint*)(xb + (size_t)r5.x * 128 + j);
                uint u6 = *(const uint*)(xb + (size_t)r6.x * 128 + j);
                uint u7 = *(const uint*)(xb + (size_t)r7.x * 128 + j);
                proc(r0, u0); proc(r1, u1); proc(r2, u2); proc(r3, u3);
                proc(r4, u4); proc(r5, u5); proc(r6, u6); proc(r7, u7);
            }
            for (; t + 3 < re; t += 4) {
                uint2 r0 = recs[t];
                uint2 r1 = recs[t + 1];
                uint2 r2 = recs[t + 2];
                uint2 r3 = recs[t + 3];
                uint u0 = *(const uint*)(xb + (size_t)r0.x * 128 + j);
                uint u1 = *(const uint*)(xb + (size_t)r1.x * 128 + j);
                uint u2 = *(const uint*)(xb + (size_t)r2.x * 128 + j);
                uint u3 = *(const uint*)(xb + (size_t)r3.x * 128 + j);
                proc(r0, u0); proc(r1, u1); proc(r2, u2); proc(r3, u3);
            }
            for (; t < re; t++) {
                uint2 r0 = recs[t];
                uint u0 = *(const uint*)(xb + (size_t)r0.x * 128 + j);
                proc(r0, u0);
            }

            int idx = (q * 128 + j) ^ ((q & 7) << 2);
            *(f2v*)&tile[idx] = accv;
            q = q2; rs = rs2; re = re2;
        }
    } else {
        float w0 = We[lane], w1 = We[64 + lane], bb = be[lane];

        int q = steal();
        int rs = 0, re = 0;
        if (q < 16) {
            rs = __builtin_amdgcn_readfirstlane(rr[2 * (n0 + q)]);
            re = __builtin_amdgcn_readfirstlane(rr[2 * (n0 + q) + 1]);
        }
        while (q < 16) {
            int q2 = steal();
            int rs2 = 0, re2 = 0;
            if (q2 < 16) {
                rs2 = __builtin_amdgcn_readfirstlane(rr[2 * (n0 + q2)]);
                re2 = __builtin_amdgcn_readfirstlane(rr[2 * (n0 + q2) + 1]);
            }
            float acc = 0.f;

            auto proc = [&](uint2 r, ushort u) {
                float ax = bf2f((ushort)(r.y & 0xFFFF));
                float ay = bf2f((ushort)(r.y >> 16));
                float m = bf2f(u) + bb;
                m = ay * w1 + m;
                m = ax * w0 + m;
                acc += fmaxf(m, 0.f);
            };

            int t = rs;
            for (; t + 7 < re; t += 8) {
                uint2 r0 = recs[t];
                uint2 r1 = recs[t + 1];
                uint2 r2 = recs[t + 2];
                uint2 r3 = recs[t + 3];
                uint2 r4 = recs[t + 4];
                uint2 r5 = recs[t + 5];
                uint2 r6 = recs[t + 6];
                uint2 r7 = recs[t + 7];
                ushort u0 = xb[(size_t)r0.x * 64 + lane];
                ushort u1 = xb[(size_t)r1.x * 64 + lane];
                ushort u2 = xb[(size_t)r2.x * 64 + lane];
                ushort u3 = xb[(size_t)r3.x * 64 + lane];
                ushort u4 = xb[(size_t)r4.x * 64 + lane];
                ushort u5 = xb[(size_t)r5.x * 64 + lane];
                ushort u6 = xb[(size_t)r6.x * 64 + lane];
                ushort u7 = xb[(size_t)r7.x * 64 + lane];
                proc(r0, u0); proc(r1, u1); proc(r2, u2); proc(r3, u3);
                proc(r4, u4); proc(r5, u5); proc(r6, u6); proc(r7, u7);
            }
            for (; t + 3 < re; t += 4) {
                uint2 r0 = recs[t];
                uint2 r1 = recs[t + 1];
                uint2 r2 = recs[t + 2];
                uint2 r3 = recs[t + 3];
                ushort u0 = xb[(size_t)r0.x * 64 + lane];
                ushort u1 = xb[(size_t)r1.x * 64 + lane];
                ushort u2 = xb[(size_t)r2.x * 64 + lane];
                ushort u3 = xb[(size_t)r3.x * 64 + lane];
                proc(r0, u0); proc(r1, u1); proc(r2, u2); proc(r3, u3);
            }
            for (; t < re; t++) {
                uint2 r0 = recs[t];
                ushort u0 = xb[(size_t)r0.x * 64 + lane];
                proc(r0, u0);
            }

            int idx = (q * 64 + lane) ^ ((q & 7) << 2);
            tile[idx] = acc;
            q = q2; rs = rs2; re = re2;
        }
    }
    __syncthreads();

    // ---- MFMA transform phase: wave handles col-tiles nt = 2*wave, 2*wave+1 ----
    {
        int l15 = lane & 15;
        int kgrp = (lane >> 4) * 8;
        int row = l15;
        int sw = (row & 7) << 2;
        int nt0 = wave * 2;
        int nt1 = nt0 + 1;
        float b0 = bn[nt0 * 16 + l15];
        float b1 = bn[nt1 * 16 + l15];
        f32x4 acc0 = {b0, b0, b0, b0};
        f32x4 acc1 = {b1, b1, b1, b1};

#pragma unroll
        for (int kk = 0; kk < K / 32; kk++) {
            int k0 = kk * 32 + kgrp;
            f32x4 p0 = *(const f32x4*)&tile[(row * K + k0) ^ sw];
            f32x4 p1 = *(const f32x4*)&tile[(row * K + k0 + 4) ^ sw];
            bf16x8 xr = *(const bf16x8*)(xb + (size_t)(n0 + row) * K + k0);
            bf16x8 a;
#pragma unroll
            for (int e = 0; e < 4; e++) {
                a[e]     = (short)f2bf(p0[e] + bf2f((ushort)xr[e]));
                a[e + 4] = (short)f2bf(p1[e] + bf2f((ushort)xr[e + 4]));
            }
            bf16x8 bf0 = *(const bf16x8*)(wnT + (size_t)(nt0 * 16 + l15) * K + k0);
            bf16x8 bf1 = *(const bf16x8*)(wnT + (size_t)(nt1 * 16 + l15) * K + k0);
            acc0 = __builtin_amdgcn_mfma_f32_16x16x32_bf16(a, bf0, acc0, 0, 0, 0);
            acc1 = __builtin_amdgcn_mfma_f32_16x16x32_bf16(a, bf1, acc1, 0, 0, 0);
        }

        int rbase = n0 + (lane >> 4) * 4;
#pragma unroll
        for (int r = 0; r < 4; r++) {
            hb[(size_t)(rbase + r) * HID + nt0 * 16 + l15] = f2bf(leaky(acc0[r]));
            hb[(size_t)(rbase + r) * HID + nt1 * 16 + l15] = f2bf(leaky(acc1[r]));
        }
    }
}

// ---------------- pooling: one wave per 64-node slab; batch sorted -> wave-uniform graph id ----------------
#define POOL_NPW 64
__global__ __launch_bounds__(256) void pool_kernel(const ushort* __restrict__ h,
                                                   const int* __restrict__ batch,
                                                   float* __restrict__ pooled) {
    int wid = (blockIdx.x * 256 + (int)threadIdx.x) >> 6;
    int lane = threadIdx.x & 63;
    int n0 = wid * POOL_NPW;
    if (n0 >= N_NODES) return;
    int n1 = n0 + POOL_NPW; if (n1 > N_NODES) n1 = N_NODES;

    int j = lane * 2;
    f2v acc = {0.f, 0.f};
    int g = __builtin_amdgcn_readfirstlane(batch[n0]);
    for (int i = n0; i < n1; i++) {
        int bg = __builtin_amdgcn_readfirstlane(batch[i]);
        if (bg != g) {
            atomicAdd(&pooled[g * HID + j], acc.x);
            atomicAdd(&pooled[g * HID + j + 1], acc.y);
            acc.x = 0.f; acc.y = 0.f;
            g = bg;
        }
        uint u = *(const uint*)(h + (size_t)i * HID + j);
        union { uint i; float f; } lo, hi;
        lo.i = u << 16;
        hi.i = u & 0xFFFF0000u;
        acc.x += lo.f;
        acc.y += hi.f;
    }
    atomicAdd(&pooled[g * HID + j], acc.x);
    atomicAdd(&pooled[g * HID + j + 1], acc.y);
}

// ---------------- head MLP ----------------

__global__ __launch_bounds__(256) void head_kernel(const float* __restrict__ pooled,
                                                   const float* __restrict__ Wh0,
                                                   const float* __restrict__ bh0,
                                                   const float* __restrict__ Wh1,
                                                   const float* __restrict__ bh1,
                                                   float* __restrict__ out) {
    __shared__ float p[HID];
    __shared__ float hid[HEAD_H];
    int g = blockIdx.x;
    int t = threadIdx.x;
    if (t < HID) p[t] = pooled[g * HID + t];
    __syncthreads();
    float acc = bh0[t];
    for (int k = 0; k < HID; k++) acc += p[k] * Wh0[k * HEAD_H + t];
    hid[t] = leaky(acc);
    __syncthreads();
    if (t < OUT_F) {
        float o = bh1[t];
        for (int k = 0; k < HEAD_H; k++) o += hid[k] * Wh1[k * OUT_F + t];
        out[g * OUT_F + t] = o;
    }
}

extern "C" void kernel_launch(void* const* d_in, const int* in_sizes, int n_in,
                              void* d_out, int out_size, void* d_ws, size_t ws_size,
                              hipStream_t stream) {
    const float* x     = (const float*)d_in[0];
    const int*   ei    = (const int*)d_in[1];
    const float* ea    = (const float*)d_in[2];
    const int*   batch = (const int*)d_in[3];
    const float* We0 = (const float*)d_in[4];
    const float* be0 = (const float*)d_in[5];
    const float* Wn0 = (const float*)d_in[6];
    const float* bn0 = (const float*)d_in[7];
    const float* We1 = (const float*)d_in[8];
    const float* be1 = (const float*)d_in[9];
    const float* Wn1 = (const float*)d_in[10];
    const float* bn1 = (const float*)d_in[11];
    const float* We2 = (const float*)d_in[12];
    const float* be2 = (const float*)d_in[13];
    const float* Wn2 = (const float*)d_in[14];
    const float* bn2 = (const float*)d_in[15];
    const float* Wh0 = (const float*)d_in[16];
    const float* bh0 = (const float*)d_in[17];
    const float* Wh1 = (const float*)d_in[18];
    const float* bh1 = (const float*)d_in[19];

    const int* src = ei;
    const int* dst = ei + N_EDGES;

    char* ws = (char*)d_ws;
    size_t o = 0;
    uint2*  recs1 = (uint2*)(ws + o); o += (size_t)NBK * SLOT * 8;        // 16.06 MB
    uint2*  recs2 = (uint2*)(ws + o); o += (size_t)NBK * SLOT * 8;        // 16.06 MB
    ushort* xb0  = (ushort*)(ws + o); o += (size_t)N_NODES * 64 * 2;      // 12.8 MB
    ushort* hbufA = (ushort*)(ws + o); o += (size_t)N_NODES * 128 * 2;    // 25.6 MB
    ushort* hbufB = (ushort*)(ws + o); o += (size_t)N_NODES * 128 * 2;    // 25.6 MB
    int*    rr   = (int*)(ws + o);    o += (size_t)N_NODES * 8 + 768;     // {beg,end} pairs
    int*    bcur = (int*)(ws + o);    o += 4096;
    ushort* wnT0 = (ushort*)(ws + o); o += 128 * 64 * 2;
    ushort* wnT1 = (ushort*)(ws + o); o += 128 * 128 * 2;
    ushort* wnT2 = (ushort*)(ws + o); o += 128 * 128 * 2;
    float*  pooled = (float*)(ws + o); o += (size_t)N_GRAPHS * HID * 4;

    // --- setup (cast + weight prep, one dispatch) ---
    setup_kernel<<<CAST_BLOCKS + 160, 256, 0, stream>>>(x, xb0, Wn0, Wn1, Wn2, wnT0, wnT1, wnT2);

    // --- slotted CSR build: bin -> order ---
    hipMemsetAsync(bcur, 0, NBK * sizeof(int), stream);
    bin_kernel<<<NCHUNKS, 256, 0, stream>>>(src, dst, (const float2*)ea, bcur, recs1);
    order_kernel<<<NBK, 256, 0, stream>>>(recs1, bcur, rr, recs2);

    const int FUSED_BLOCKS = N_NODES / 16;  // 6250

    // --- layer 0 (64 -> 128) ---
    gine_fused<64><<<FUSED_BLOCKS, 256, 0, stream>>>(xb0, recs2, rr, We0, be0, wnT0, bn0, hbufA);
    // --- layer 1 (128 -> 128) ---
    gine_fused<128><<<FUSED_BLOCKS, 256, 0, stream>>>(hbufA, recs2, rr, We1, be1, wnT1, bn1, hbufB);
    // --- layer 2 (128 -> 128) ---
    gine_fused<128><<<FUSED_BLOCKS, 256, 0, stream>>>(hbufB, recs2, rr, We2, be2, wnT2, bn2, hbufA);

    // --- pool + head ---
    hipMemsetAsync(pooled, 0, (size_t)N_GRAPHS * HID * sizeof(float), stream);
    pool_kernel<<<(N_NODES / POOL_NPW + 3) / 4, 256, 0, stream>>>(hbufA, batch, pooled);
    head_kernel<<<N_GRAPHS, 256, 0, stream>>>(pooled, Wh0, bh0, Wh1, bh1, (float*)d_out);
}

// Round 15
// 337.806 us; speedup vs baseline: 1.0154x; 1.0154x over previous
//
#include <hip/hip_runtime.h>
#include <hip/hip_bf16.h>

#define N_NODES 100000
#define N_EDGES 1600000
#define F_IN 64
#define HID 128
#define HEAD_H 256
#define OUT_F 32
#define N_GRAPHS 512
#define NBK 98        // coarse buckets (dst >> 10)
#define SLOT 20480    // fixed records per bucket (mean 16384, sigma ~127)
#define BCHUNK 2048   // edges per bin-kernel block
#define NCHUNKS ((N_EDGES + BCHUNK - 1) / BCHUNK)  // 782
#define CAST_BLOCKS (N_NODES * F_IN / 2 / 256)     // 12500

typedef float f2v __attribute__((ext_vector_type(2)));
typedef short bf16x8 __attribute__((ext_vector_type(8)));
typedef float f32x4 __attribute__((ext_vector_type(4)));

__device__ __forceinline__ float leaky(float v) {
    return v >= 0.f ? v : 0.01f * v;
}

__device__ __forceinline__ float bf2f(ushort u) {
    union { uint i; float f; } c; c.i = ((uint)u) << 16; return c.f;
}

__device__ __forceinline__ ushort f2bf(float f) {
    union { float f; uint i; } c; c.f = f;
    uint r = c.i + 0x7FFF + ((c.i >> 16) & 1);
    return (ushort)(r >> 16);
}

// ---------------- setup: cast x -> bf16 AND prep transposed bf16 weights (one dispatch) ----------------
__global__ __launch_bounds__(256) void setup_kernel(const float* __restrict__ x,
                                                    ushort* __restrict__ xb,
                                                    const float* __restrict__ Wn0,
                                                    const float* __restrict__ Wn1,
                                                    const float* __restrict__ Wn2,
                                                    ushort* __restrict__ w0T,
                                                    ushort* __restrict__ w1T,
                                                    ushort* __restrict__ w2T) {
    int b = blockIdx.x;
    if (b < CAST_BLOCKS) {
        int i = b * 256 + threadIdx.x;  // handles 2 elems
        float2 v = ((const float2*)x)[i];
        uint u = (uint)f2bf(v.x) | ((uint)f2bf(v.y) << 16);
        ((uint*)xb)[i] = u;
    } else {
        int id = (b - CAST_BLOCKS) * 256 + threadIdx.x;
        if (id < 128 * 64) {
            int j = id / 64, k = id % 64;
            w0T[id] = f2bf(Wn0[k * 128 + j]);
        } else if (id < 128 * 64 + 128 * 128) {
            int t = id - 128 * 64; int j = t / 128, k = t % 128;
            w1T[t] = f2bf(Wn1[k * 128 + j]);
        } else if (id < 128 * 64 + 2 * 128 * 128) {
            int t = id - 128 * 64 - 128 * 128; int j = t / 128, k = t % 128;
            w2T[t] = f2bf(Wn2[k * 128 + j]);
        }
    }
}

// ---------------- slotted-bucket CSR build ----------------
// bcur[b] holds COUNTS (memset 0); slot base b*SLOT added where needed.

// pass 1: bin edges by dst>>10 into fixed bucket slots of recs1
// record: x = src | (dloc<<22), y = packed bf16 edge attrs. Order within bucket arbitrary.
__global__ __launch_bounds__(256) void bin_kernel(const int* __restrict__ src,
                                                  const int* __restrict__ dst,
                                                  const float2* __restrict__ ea,
                                                  int* __restrict__ bcur,
                                                  uint2* __restrict__ recs1) {
    __shared__ int hist[NBK], tmp[NBK], offs[NBK], cur[NBK], gbase[NBK];
    __shared__ uint2 stage[BCHUNK];
    __shared__ unsigned char sbid[BCHUNK];

    int tid = threadIdx.x;
    int e0 = blockIdx.x * BCHUNK;
    int nn = N_EDGES - e0; if (nn > BCHUNK) nn = BCHUNK;  // 2048 or 512, both %4==0

    if (tid < NBK) hist[tid] = 0;
    __syncthreads();

    // phase A: LDS histogram over this chunk (int4 loads)
    for (int i0 = tid * 4; i0 < nn; i0 += 1024) {
        int4 d4 = *(const int4*)(dst + e0 + i0);
        atomicAdd(&hist[d4.x >> 10], 1);
        atomicAdd(&hist[d4.y >> 10], 1);
        atomicAdd(&hist[d4.z >> 10], 1);
        atomicAdd(&hist[d4.w >> 10], 1);
    }
    __syncthreads();

    // scan hist -> offs (exclusive)
    if (tid < NBK) tmp[tid] = hist[tid];
    __syncthreads();
    for (int off = 1; off < NBK; off <<= 1) {
        int u = (tid < NBK && tid >= off) ? tmp[tid - off] : 0;
        __syncthreads();
        if (tid < NBK) tmp[tid] += u;
        __syncthreads();
    }
    if (tid < NBK) {
        int ex = tmp[tid] - hist[tid];
        offs[tid] = ex;
        cur[tid] = ex;
        gbase[tid] = (hist[tid] > 0) ? (tid * SLOT + atomicAdd(&bcur[tid], hist[tid])) : 0;
    }
    __syncthreads();

    // phase B: place records into LDS, bucket-sorted (vectorized loads)
    for (int i0 = tid * 4; i0 < nn; i0 += 1024) {
        int e = e0 + i0;
        int4 d4 = *(const int4*)(dst + e);
        int4 s4 = *(const int4*)(src + e);
        float4 ea01 = *(const float4*)(ea + e);
        float4 ea23 = *(const float4*)(ea + e + 2);
#pragma unroll
        for (int k = 0; k < 4; k++) {
            int d = (k == 0) ? d4.x : (k == 1) ? d4.y : (k == 2) ? d4.z : d4.w;
            int s = (k == 0) ? s4.x : (k == 1) ? s4.y : (k == 2) ? s4.z : s4.w;
            float aex = (k == 0) ? ea01.x : (k == 1) ? ea01.z : (k == 2) ? ea23.x : ea23.z;
            float aey = (k == 0) ? ea01.y : (k == 1) ? ea01.w : (k == 2) ? ea23.y : ea23.w;
            int b = d >> 10;
            uint2 r;
            r.x = (uint)s | ((uint)(d & 1023) << 22);
            r.y = (uint)f2bf(aex) | ((uint)f2bf(aey) << 16);
            int pos = atomicAdd(&cur[b], 1);
            stage[pos] = r;
            sbid[pos] = (unsigned char)b;
        }
    }
    __syncthreads();

    // phase C: flush contiguous per-bucket runs
    for (int i = tid; i < nn; i += 256) {
        int b = sbid[i];
        recs1[gbase[b] + (i - offs[b])] = stage[i];
    }
}

// pass 2: per bucket, build rr[{beg,end}] (LDS) + order records into exact slots of recs2
__global__ __launch_bounds__(256) void order_kernel(const uint2* __restrict__ recs1,
                                                    const int* __restrict__ bcur,
                                                    int* __restrict__ rr,
                                                    uint2* __restrict__ recs2) {
    __shared__ int h[1024];
    __shared__ int ssum[256];
    int b = blockIdx.x;
    int tid = threadIdx.x;
    int base = b * SLOT;
    int end = base + bcur[b];

    for (int i = tid; i < 1024; i += 256) h[i] = 0;
    __syncthreads();

    // LDS histogram of node-local ids over this bucket's filled region
    for (int t = base + tid; t < end; t += 256) {
        atomicAdd(&h[recs1[t].x >> 22], 1);
    }
    __syncthreads();

    // scan 1024 in LDS: thread owns 4 entries + 256-ladder
    int i4 = tid * 4;
    int a0 = h[i4], a1 = h[i4 + 1], a2 = h[i4 + 2], a3 = h[i4 + 3];
    int s = a0 + a1 + a2 + a3;
    ssum[tid] = s;
    __syncthreads();
    for (int off = 1; off < 256; off <<= 1) {
        int u = (tid >= off) ? ssum[tid - off] : 0;
        __syncthreads();
        ssum[tid] += u;
        __syncthreads();
    }
    int pre = base + ssum[tid] - s;  // absolute exclusive prefix within slotted space
    int c0 = pre, c1 = pre + a0, c2 = c1 + a1, c3 = c2 + a2;
    h[i4] = c0; h[i4 + 1] = c1; h[i4 + 2] = c2; h[i4 + 3] = c3;

    // write rr (beg,end interleaved) for this bucket's nodes
    int n = (b << 10) + i4;
    if (n + 4 <= N_NODES) {
        *(int4*)(rr + 2 * n)     = make_int4(c0, c0 + a0, c1, c1 + a1);
        *(int4*)(rr + 2 * n + 4) = make_int4(c2, c2 + a2, c3, c3 + a3);
    } else {
        if (n + 0 < N_NODES) { rr[2 * n + 0] = c0; rr[2 * n + 1] = c0 + a0; }
        if (n + 1 < N_NODES) { rr[2 * n + 2] = c1; rr[2 * n + 3] = c1 + a1; }
        if (n + 2 < N_NODES) { rr[2 * n + 4] = c2; rr[2 * n + 5] = c2 + a2; }
        if (n + 3 < N_NODES) { rr[2 * n + 6] = c3; rr[2 * n + 7] = c3 + a3; }
    }
    __syncthreads();

    // place records into exact slots
    for (int t = base + tid; t < end; t += 256) {
        uint2 r = recs1[t];
        int pos = atomicAdd(&h[r.x >> 22], 1);
        recs2[pos] = make_uint2(r.x & 0x3FFFFFu, r.y);
    }
}

// ---------------- fused GINE layer (round-13 form: simple steal + LDS tile + MFMA epilogue) ----------------
// 256 threads = 4 waves; block owns 16 nodes. Waves steal nodes one at a time from
// an LDS counter (lane-0 atomic + readfirstlane). Hot loop = round-8 gather
// (register acc, 8-deep unroll, no per-edge branches/LDS). Finished rows ->
// swizzled fp32 LDS tile (one ds_write per node). One barrier, then the 4 waves
// run the MFMA transform (residual +x folded at bf16 conversion), write hb.

template <int K>
__global__ __launch_bounds__(256) void gine_fused(const ushort* __restrict__ xb,
                                                  const uint2* __restrict__ recs,
                                                  const int* __restrict__ rr,
                                                  const float* __restrict__ We,
                                                  const float* __restrict__ be,
                                                  const ushort* __restrict__ wnT,
                                                  const float* __restrict__ bn,
                                                  ushort* __restrict__ hb) {
    __shared__ float tile[16 * K];
    __shared__ int node_ctr;
    int tid = threadIdx.x;
    int wave = tid >> 6;
    int lane = tid & 63;
    int n0 = blockIdx.x * 16;

    if (tid == 0) node_ctr = 0;
    __syncthreads();

    // ---- gather phase: dynamic node grab (single-node state) ----
    if constexpr (K == 128) {
        int j = lane * 2;
        f2v w0v = {We[j], We[j + 1]};
        f2v w1v = {We[128 + j], We[128 + j + 1]};
        f2v bbv = {be[j], be[j + 1]};
        const f2v zero = {0.f, 0.f};

        for (;;) {
            int q = 0;
            if (lane == 0) q = atomicAdd(&node_ctr, 1);
            q = __builtin_amdgcn_readfirstlane(q);
            if (q >= 16) break;
            int node = n0 + q;
            int rs = __builtin_amdgcn_readfirstlane(rr[2 * node]);
            int re = __builtin_amdgcn_readfirstlane(rr[2 * node + 1]);
            f2v accv = {0.f, 0.f};

            auto proc = [&](uint2 r, uint u) {
                float ax = bf2f((ushort)(r.y & 0xFFFF));
                float ay = bf2f((ushort)(r.y >> 16));
                union { uint i; float f; } lo, hi;
                lo.i = u << 16;
                hi.i = u & 0xFFFF0000u;
                f2v xv = {lo.f, hi.f};
                f2v m = xv + bbv;
                m = ay * w1v + m;
                m = ax * w0v + m;
                m = __builtin_elementwise_max(m, zero);
                accv += m;
            };

            int t = rs;
            for (; t + 7 < re; t += 8) {
                uint2 r0 = recs[t];
                uint2 r1 = recs[t + 1];
                uint2 r2 = recs[t + 2];
                uint2 r3 = recs[t + 3];
                uint2 r4 = recs[t + 4];
                uint2 r5 = recs[t + 5];
                uint2 r6 = recs[t + 6];
                uint2 r7 = recs[t + 7];
                uint u0 = *(const uint*)(xb + (size_t)r0.x * 128 + j);
                uint u1 = *(const uint*)(xb + (size_t)r1.x * 128 + j);
                uint u2 = *(const uint*)(xb + (size_t)r2.x * 128 + j);
                uint u3 = *(const uint*)(xb + (size_t)r3.x * 128 + j);
                uint u4 = *(const uint*)(xb + (size_t)r4.x * 128 + j);
                uint u5 = *(const uint*)(xb + (size_t)r5.x * 128 + j);
                uint u6 = *(const uint*)(xb + (size_t)r6.x * 128 + j);
                uint u7 = *(const uint*)(xb + (size_t)r7.x * 128 + j);
                proc(r0, u0); proc(r1, u1); proc(r2, u2); proc(r3, u3);
                proc(r4, u4); proc(r5, u5); proc(r6, u6); proc(r7, u7);
            }
            for (; t + 3 < re; t += 4) {
                uint2 r0 = recs[t];
                uint2 r1 = recs[t + 1];
                uint2 r2 = recs[t + 2];
                uint2 r3 = recs[t + 3];
                uint u0 = *(const uint*)(xb + (size_t)r0.x * 128 + j);
                uint u1 = *(const uint*)(xb + (size_t)r1.x * 128 + j);
                uint u2 = *(const uint*)(xb + (size_t)r2.x * 128 + j);
                uint u3 = *(const uint*)(xb + (size_t)r3.x * 128 + j);
                proc(r0, u0); proc(r1, u1); proc(r2, u2); proc(r3, u3);
            }
            for (; t < re; t++) {
                uint2 r0 = recs[t];
                uint u0 = *(const uint*)(xb + (size_t)r0.x * 128 + j);
                proc(r0, u0);
            }

            int idx = (q * 128 + j) ^ ((q & 7) << 2);
            *(f2v*)&tile[idx] = accv;
        }
    } else {
        float w0 = We[lane], w1 = We[64 + lane], bb = be[lane];

        for (;;) {
            int q = 0;
            if (lane == 0) q = atomicAdd(&node_ctr, 1);
            q = __builtin_amdgcn_readfirstlane(q);
            if (q >= 16) break;
            int node = n0 + q;
            int rs = __builtin_amdgcn_readfirstlane(rr[2 * node]);
            int re = __builtin_amdgcn_readfirstlane(rr[2 * node + 1]);
            float acc = 0.f;

            auto proc = [&](uint2 r, ushort u) {
                float ax = bf2f((ushort)(r.y & 0xFFFF));
                float ay = bf2f((ushort)(r.y >> 16));
                float m = bf2f(u) + bb;
                m = ay * w1 + m;
                m = ax * w0 + m;
                acc += fmaxf(m, 0.f);
            };

            int t = rs;
            for (; t + 7 < re; t += 8) {
                uint2 r0 = recs[t];
                uint2 r1 = recs[t + 1];
                uint2 r2 = recs[t + 2];
                uint2 r3 = recs[t + 3];
                uint2 r4 = recs[t + 4];
                uint2 r5 = recs[t + 5];
                uint2 r6 = recs[t + 6];
                uint2 r7 = recs[t + 7];
                ushort u0 = xb[(size_t)r0.x * 64 + lane];
                ushort u1 = xb[(size_t)r1.x * 64 + lane];
                ushort u2 = xb[(size_t)r2.x * 64 + lane];
                ushort u3 = xb[(size_t)r3.x * 64 + lane];
                ushort u4 = xb[(size_t)r4.x * 64 + lane];
                ushort u5 = xb[(size_t)r5.x * 64 + lane];
                ushort u6 = xb[(size_t)r6.x * 64 + lane];
                ushort u7 = xb[(size_t)r7.x * 64 + lane];
                proc(r0, u0); proc(r1, u1); proc(r2, u2); proc(r3, u3);
                proc(r4, u4); proc(r5, u5); proc(r6, u6); proc(r7, u7);
            }
            for (; t + 3 < re; t += 4) {
                uint2 r0 = recs[t];
                uint2 r1 = recs[t + 1];
                uint2 r2 = recs[t + 2];
                uint2 r3 = recs[t + 3];
                ushort u0 = xb[(size_t)r0.x * 64 + lane];
                ushort u1 = xb[(size_t)r1.x * 64 + lane];
                ushort u2 = xb[(size_t)r2.x * 64 + lane];
                ushort u3 = xb[(size_t)r3.x * 64 + lane];
                proc(r0, u0); proc(r1, u1); proc(r2, u2); proc(r3, u3);
            }
            for (; t < re; t++) {
                uint2 r0 = recs[t];
                ushort u0 = xb[(size_t)r0.x * 64 + lane];
                proc(r0, u0);
            }

            int idx = (q * 64 + lane) ^ ((q & 7) << 2);
            tile[idx] = acc;
        }
    }
    __syncthreads();

    // ---- MFMA transform phase: wave handles col-tiles nt = 2*wave, 2*wave+1 ----
    {
        int l15 = lane & 15;
        int kgrp = (lane >> 4) * 8;
        int row = l15;
        int sw = (row & 7) << 2;
        int nt0 = wave * 2;
        int nt1 = nt0 + 1;
        float b0 = bn[nt0 * 16 + l15];
        float b1 = bn[nt1 * 16 + l15];
        f32x4 acc0 = {b0, b0, b0, b0};
        f32x4 acc1 = {b1, b1, b1, b1};

#pragma unroll
        for (int kk = 0; kk < K / 32; kk++) {
            int k0 = kk * 32 + kgrp;
            f32x4 p0 = *(const f32x4*)&tile[(row * K + k0) ^ sw];
            f32x4 p1 = *(const f32x4*)&tile[(row * K + k0 + 4) ^ sw];
            bf16x8 xr = *(const bf16x8*)(xb + (size_t)(n0 + row) * K + k0);
            bf16x8 a;
#pragma unroll
            for (int e = 0; e < 4; e++) {
                a[e]     = (short)f2bf(p0[e] + bf2f((ushort)xr[e]));
                a[e + 4] = (short)f2bf(p1[e] + bf2f((ushort)xr[e + 4]));
            }
            bf16x8 bf0 = *(const bf16x8*)(wnT + (size_t)(nt0 * 16 + l15) * K + k0);
            bf16x8 bf1 = *(const bf16x8*)(wnT + (size_t)(nt1 * 16 + l15) * K + k0);
            acc0 = __builtin_amdgcn_mfma_f32_16x16x32_bf16(a, bf0, acc0, 0, 0, 0);
            acc1 = __builtin_amdgcn_mfma_f32_16x16x32_bf16(a, bf1, acc1, 0, 0, 0);
        }

        int rbase = n0 + (lane >> 4) * 4;
#pragma unroll
        for (int r = 0; r < 4; r++) {
            hb[(size_t)(rbase + r) * HID + nt0 * 16 + l15] = f2bf(leaky(acc0[r]));
            hb[(size_t)(rbase + r) * HID + nt1 * 16 + l15] = f2bf(leaky(acc1[r]));
        }
    }
}

// ---------------- pooling: one wave per 64-node slab; batch sorted -> wave-uniform graph id ----------------
#define POOL_NPW 64
__global__ __launch_bounds__(256) void pool_kernel(const ushort* __restrict__ h,
                                                   const int* __restrict__ batch,
                                                   float* __restrict__ pooled) {
    int wid = (blockIdx.x * 256 + (int)threadIdx.x) >> 6;
    int lane = threadIdx.x & 63;
    int n0 = wid * POOL_NPW;
    if (n0 >= N_NODES) return;
    int n1 = n0 + POOL_NPW; if (n1 > N_NODES) n1 = N_NODES;

    int j = lane * 2;
    f2v acc = {0.f, 0.f};
    int g = __builtin_amdgcn_readfirstlane(batch[n0]);
    for (int i = n0; i < n1; i++) {
        int bg = __builtin_amdgcn_readfirstlane(batch[i]);
        if (bg != g) {
            atomicAdd(&pooled[g * HID + j], acc.x);
            atomicAdd(&pooled[g * HID + j + 1], acc.y);
            acc.x = 0.f; acc.y = 0.f;
            g = bg;
        }
        uint u = *(const uint*)(h + (size_t)i * HID + j);
        union { uint i; float f; } lo, hi;
        lo.i = u << 16;
        hi.i = u & 0xFFFF0000u;
        acc.x += lo.f;
        acc.y += hi.f;
    }
    atomicAdd(&pooled[g * HID + j], acc.x);
    atomicAdd(&pooled[g * HID + j + 1], acc.y);
}

// ---------------- head MLP ----------------

__global__ __launch_bounds__(256) void head_kernel(const float* __restrict__ pooled,
                                                   const float* __restrict__ Wh0,
                                                   const float* __restrict__ bh0,
                                                   const float* __restrict__ Wh1,
                                                   const float* __restrict__ bh1,
                                                   float* __restrict__ out) {
    __shared__ float p[HID];
    __shared__ float hid[HEAD_H];
    int g = blockIdx.x;
    int t = threadIdx.x;
    if (t < HID) p[t] = pooled[g * HID + t];
    __syncthreads();
    float acc = bh0[t];
    for (int k = 0; k < HID; k++) acc += p[k] * Wh0[k * HEAD_H + t];
    hid[t] = leaky(acc);
    __syncthreads();
    if (t < OUT_F) {
        float o = bh1[t];
        for (int k = 0; k < HEAD_H; k++) o += hid[k] * Wh1[k * OUT_F + t];
        out[g * OUT_F + t] = o;
    }
}

extern "C" void kernel_launch(void* const* d_in, const int* in_sizes, int n_in,
                              void* d_out, int out_size, void* d_ws, size_t ws_size,
                              hipStream_t stream) {
    const float* x     = (const float*)d_in[0];
    const int*   ei    = (const int*)d_in[1];
    const float* ea    = (const float*)d_in[2];
    const int*   batch = (const int*)d_in[3];
    const float* We0 = (const float*)d_in[4];
    const float* be0 = (const float*)d_in[5];
    const float* Wn0 = (const float*)d_in[6];
    const float* bn0 = (const float*)d_in[7];
    const float* We1 = (const float*)d_in[8];
    const float* be1 = (const float*)d_in[9];
    const float* Wn1 = (const float*)d_in[10];
    const float* bn1 = (const float*)d_in[11];
    const float* We2 = (const float*)d_in[12];
    const float* be2 = (const float*)d_in[13];
    const float* Wn2 = (const float*)d_in[14];
    const float* bn2 = (const float*)d_in[15];
    const float* Wh0 = (const float*)d_in[16];
    const float* bh0 = (const float*)d_in[17];
    const float* Wh1 = (const float*)d_in[18];
    const float* bh1 = (const float*)d_in[19];

    const int* src = ei;
    const int* dst = ei + N_EDGES;

    char* ws = (char*)d_ws;
    size_t o = 0;
    uint2*  recs1 = (uint2*)(ws + o); o += (size_t)NBK * SLOT * 8;        // 16.06 MB
    uint2*  recs2 = (uint2*)(ws + o); o += (size_t)NBK * SLOT * 8;        // 16.06 MB
    ushort* xb0  = (ushort*)(ws + o); o += (size_t)N_NODES * 64 * 2;      // 12.8 MB
    ushort* hbufA = (ushort*)(ws + o); o += (size_t)N_NODES * 128 * 2;    // 25.6 MB
    ushort* hbufB = (ushort*)(ws + o); o += (size_t)N_NODES * 128 * 2;    // 25.6 MB
    int*    rr   = (int*)(ws + o);    o += (size_t)N_NODES * 8 + 768;     // {beg,end} pairs
    int*    bcur = (int*)(ws + o);    o += 4096;
    ushort* wnT0 = (ushort*)(ws + o); o += 128 * 64 * 2;
    ushort* wnT1 = (ushort*)(ws + o); o += 128 * 128 * 2;
    ushort* wnT2 = (ushort*)(ws + o); o += 128 * 128 * 2;
    float*  pooled = (float*)(ws + o); o += (size_t)N_GRAPHS * HID * 4;

    // --- setup (cast + weight prep, one dispatch) ---
    setup_kernel<<<CAST_BLOCKS + 160, 256, 0, stream>>>(x, xb0, Wn0, Wn1, Wn2, wnT0, wnT1, wnT2);

    // --- slotted CSR build: bin -> order ---
    hipMemsetAsync(bcur, 0, NBK * sizeof(int), stream);
    bin_kernel<<<NCHUNKS, 256, 0, stream>>>(src, dst, (const float2*)ea, bcur, recs1);
    order_kernel<<<NBK, 256, 0, stream>>>(recs1, bcur, rr, recs2);

    const int FUSED_BLOCKS = N_NODES / 16;  // 6250

    // --- layer 0 (64 -> 128) ---
    gine_fused<64><<<FUSED_BLOCKS, 256, 0, stream>>>(xb0, recs2, rr, We0, be0, wnT0, bn0, hbufA);
    // --- layer 1 (128 -> 128) ---
    gine_fused<128><<<FUSED_BLOCKS, 256, 0, stream>>>(hbufA, recs2, rr, We1, be1, wnT1, bn1, hbufB);
    // --- layer 2 (128 -> 128) ---
    gine_fused<128><<<FUSED_BLOCKS, 256, 0, stream>>>(hbufB, recs2, rr, We2, be2, wnT2, bn2, hbufA);

    // --- pool + head ---
    hipMemsetAsync(pooled, 0, (size_t)N_GRAPHS * HID * sizeof(float), stream);
    pool_kernel<<<(N_NODES / POOL_NPW + 3) / 4, 256, 0, stream>>>(hbufA, batch, pooled);
    head_kernel<<<N_GRAPHS, 256, 0, stream>>>(pooled, Wh0, bh0, Wh1, bh1, (float*)d_out);
}